// Round 11
// baseline (16118.324 us; speedup 1.0000x reference)
//
#include <hip/hip_runtime.h>
#include <hip/hip_bf16.h>
#include <stdint.h>

// ---------------------------------------------------------------------------
// Bidirectional 5-layer LSTM (all-sigmoid), B=16, T=1024, D=1024, U=512.
// R13 = R3 rec (byte-identical protocol, blocks 0..31) + 96 consumer blocks
// computing gemm(l+1) from the progressively produced y — in the R3 204MB
// workspace (no fallback):
//   - xz overwritten IN PLACE: rec(l) consumes chunk (dir,t) at step t /
//     1023-t; gemm(l+1) writes the same addresses only after its pacers
//     witness chain-step >= consumption+32 -> write-behind-read-frontier.
//   - DIR-CORRECT pacers (R12 bug fixed): chains are independent, so each
//     tile waits on BOTH dir0 h(t=tt0+47) and dir1 h(t=1023-(1055-tt0)).
//     Within a dir, swg0 at step S implies all chain blocks >= S-1, and every
//     rec step ends with a vmcnt(0) drain -> tile lines >=31 steps settled
//     when staged (R5/R9 no-racing law honored for y reads AND xz writes).
//   - y polls agent-scope atomics (R7 lesson); rec role untouched (R12
//     measured the merged binary's rec at champion speed, VGPR 96).
//   - Wt single-buffered (transpose(l+1) before fused rec(l)); Ut single-
//     buffered (transpose(l+1) after rec(l)); deadlock impossible (gemm
//     blocks only read; rec never waits on gemm).
// ---------------------------------------------------------------------------

typedef __attribute__((ext_vector_type(8))) short short8;
typedef __attribute__((ext_vector_type(4))) float f32x4;

union U128 { uint4 u; short8 s; };
static __device__ __forceinline__ short8 as_short8(uint4 v) { U128 x; x.u = v; return x.s; }

static __device__ __forceinline__ float sigf(float x) { return 1.0f / (1.0f + __expf(-x)); }

static __device__ __forceinline__ uint32_t f2bfbits(float f) {
  union { float f; uint32_t u; } x; x.f = f;
  return (x.u + 0x7fffu + ((x.u >> 16) & 1u)) >> 16;   // RNE; h in (0,1), no NaN
}
static __device__ __forceinline__ float bflo(uint32_t v) {
  union { uint32_t u; float f; } x; x.u = v << 16; return x.f;
}
static __device__ __forceinline__ float bfhi(uint32_t v) {
  union { uint32_t u; float f; } x; x.u = v & 0xffff0000u; return x.f;
}
static __device__ __forceinline__ bool qok(unsigned long long v) {
  return ((uint32_t)v != 0u) & ((uint32_t)(v >> 32) != 0u);
}

// ---------------- x (fp32) -> bf16 ----------------
__global__ __launch_bounds__(256) void f32_to_bf16_k(const float* __restrict__ in,
                                                     __hip_bfloat16* __restrict__ out,
                                                     int n4) {
  int i = blockIdx.x * 256 + threadIdx.x;
  if (i < n4) {
    float4 v = ((const float4*)in)[i];
    uint32_t lo = f2bfbits(v.x) | (f2bfbits(v.y) << 16);
    uint32_t hi = f2bfbits(v.z) | (f2bfbits(v.w) << 16);
    ((uint2*)out)[i] = make_uint2(lo, hi);
  }
}

// ---------------- [2][R][2048] fp32 -> [2][2048][R] bf16 transpose ----------------
__global__ __launch_bounds__(256) void transpose_bf16_k(const float* __restrict__ in,
                                                        __hip_bfloat16* __restrict__ outp,
                                                        int R) {
  __shared__ float tile[64][65];
  int d = blockIdx.z;
  int k0 = blockIdx.x * 64;
  int c0 = blockIdx.y * 64;
  const float* inb = in + (size_t)d * R * 2048;
  __hip_bfloat16* ob = outp + (size_t)d * 2048 * R;
  int col = threadIdx.x & 63, rr = threadIdx.x >> 6;
#pragma unroll
  for (int i = 0; i < 16; ++i) {
    int r = rr + i * 4;
    tile[r][col] = inb[(size_t)(k0 + r) * 2048 + c0 + col];
  }
  __syncthreads();
#pragma unroll
  for (int i = 0; i < 16; ++i) {
    int r = rr + i * 4;
    ob[(size_t)(c0 + r) * R + k0 + col] = __float2bfloat16(tile[col][r]);
  }
}

// ---------------- standalone xz GEMM (layer 0 prologue) ----------------
// Output layout: xz[dir][swg(16)][t(1024)][q(4)][b(16)][j(32)]  (4KB per (dir,swg,t))
__global__ __launch_bounds__(256) void gemm_xz_k(const __hip_bfloat16* __restrict__ y,
                                                 const __hip_bfloat16* __restrict__ Wt,
                                                 const float* __restrict__ bias,
                                                 __hip_bfloat16* __restrict__ xz) {
  __shared__ uint4 Asl[8 * 2 * 64];
  __shared__ uint4 Bsl[8 * 2 * 64];
  int m0 = blockIdx.x * 128;
  int dir = blockIdx.y >> 4;
  int n0 = (blockIdx.y & 15) * 128;
  int tid = threadIdx.x, lane = tid & 63, wv = tid >> 6;
  int wm = wv & 1, wn = wv >> 1;
  const __hip_bfloat16* Wd = Wt + (size_t)dir * 2048 * 1024;
  f32x4 acc[4][4] = {};
  for (int kb = 0; kb < 1024; kb += 64) {
    __syncthreads();
#pragma unroll
    for (int i = 0; i < 4; ++i) {
      int slot = i * 256 + tid;
      int ln = slot & 63, kc = (slot >> 6) & 1, mt = slot >> 7;
      int row = mt * 16 + (ln & 15);
      int kk = kc * 32 + (ln >> 4) * 8;
      Asl[slot] = *(const uint4*)(y + (size_t)(m0 + row) * 1024 + kb + kk);
      Bsl[slot] = *(const uint4*)(Wd + (size_t)(n0 + row) * 1024 + kb + kk);
    }
    __syncthreads();
#pragma unroll
    for (int kc = 0; kc < 2; ++kc) {
      short8 af[4], bf[4];
#pragma unroll
      for (int i = 0; i < 4; ++i) {
        af[i] = as_short8(Asl[((wm * 4 + i) * 2 + kc) * 64 + lane]);
        bf[i] = as_short8(Bsl[((wn * 4 + i) * 2 + kc) * 64 + lane]);
      }
#pragma unroll
      for (int i = 0; i < 4; ++i)
#pragma unroll
        for (int j = 0; j < 4; ++j)
          acc[i][j] = __builtin_amdgcn_mfma_f32_16x16x32_bf16(af[i], bf[j], acc[i][j], 0, 0, 0);
    }
  }
  int cq = lane >> 4, cn = lane & 15;
#pragma unroll
  for (int i = 0; i < 4; ++i)
#pragma unroll
    for (int j = 0; j < 4; ++j) {
      int n_g = n0 + (wn * 4 + j) * 16 + cn;
      int q = n_g >> 9, u = n_g & 511, swg = u >> 5, jj = u & 31;
      float bv = bias[dir * 2048 + n_g];
#pragma unroll
      for (int r = 0; r < 4; ++r) {
        int m = m0 + (wm * 4 + i) * 16 + cq * 4 + r;
        int bb = m >> 10, t = m & 1023;
        size_t addr = (((size_t)(dir * 16 + swg) * 1024 + t) * 2048) + (q * 16 + bb) * 32 + jj;
        xz[addr] = __float2bfloat16(acc[i][j][r] + bv);
      }
    }
}

// ---------------- fused: rec(l) [blocks 0..31] + gemm(l+1) [blocks 32..127] ----------------
// xz and xznext alias (in-place overwrite) -> no __restrict__ on them.
__global__ __launch_bounds__(256) void lstm_rec_k(const __hip_bfloat16* __restrict__ Ut,
                                                  const __hip_bfloat16* xz,
                                                  __hip_bfloat16* __restrict__ ynext,   // pre-zeroed
                                                  float* __restrict__ outf,
                                                  const __hip_bfloat16* __restrict__ Wtn,
                                                  const float* __restrict__ biasn,
                                                  __hip_bfloat16* xznext) {
  extern __shared__ char smem[];
  int tid = threadIdx.x, lane = tid & 63, wv = tid >> 6;

  if (blockIdx.x < 32) {
    // ================= rec role: byte-identical R3 =================
    uint4* uh = (uint4*)smem;                                 // 8192 x 16B
    __hip_bfloat16* hbuf = (__hip_bfloat16*)(smem + 131072);  // [16][520]
    float* zbuf = (float*)(smem + 147712);                    // [16][128]
    __hip_bfloat16* xbuf = (__hip_bfloat16*)(smem + 155904);  // [2048]
    int dir = blockIdx.x & 1;
    int swg = blockIdx.x >> 1;
    int u0 = swg * 32;
    int quad = lane >> 4, l15 = lane & 15;
    const __hip_bfloat16* Ud = Ut + (size_t)dir * 2048 * 512;

#pragma unroll 4
    for (int i = 0; i < 32; ++i) {
      int slot = i * 256 + tid;
      int ls = slot & 63, kc = (slot >> 6) & 15, nt = slot >> 10;
      int n_g = (nt >> 1) * 512 + u0 + (nt & 1) * 16 + (ls & 15);
      int k = kc * 32 + (ls >> 4) * 8;
      uh[slot] = *(const uint4*)(Ud + (size_t)n_g * 512 + k);
    }
    __syncthreads();

    int nt0 = wv * 2, nt1 = wv * 2 + 1;
    int pb = tid >> 4, pj = (tid & 15) * 2;
    float c0 = 0.f, c1 = 0.f;

    int t0 = dir ? 1023 : 0;
    const uint4* xp0 = (const uint4*)(xz + ((size_t)(dir * 16 + swg) * 1024 + t0) * 2048) + tid;
    uint4 xcur = *xp0;

    for (int s = 0; s < 1024; ++s) {
      int t = dir ? (1023 - s) : s;
      uint4 xnxt;
      if (s < 1023) {
        int tn = dir ? (1022 - s) : (s + 1);
        xnxt = *((const uint4*)(xz + ((size_t)(dir * 16 + swg) * 1024 + tn) * 2048) + tid);
      }
      f32x4 z0 = {}, z1 = {};
      if (s > 0) {
        int tprev = dir ? (t + 1) : (t - 1);
        unsigned long long hv[8];
        const unsigned long long* gp[8];
#pragma unroll
        for (int i = 0; i < 4; ++i) {
          int v = i * 2048 + tid * 8;
          int bb = v >> 9, col = v & 511;
          const unsigned long long* g =
              (const unsigned long long*)(ynext + ((size_t)bb * 1024 + tprev) * 1024 + dir * 512 + col);
          gp[2 * i] = g;
          gp[2 * i + 1] = g + 1;
        }
#pragma unroll
        for (int i = 0; i < 8; ++i)
          hv[i] = __hip_atomic_load(gp[i], __ATOMIC_RELAXED, __HIP_MEMORY_SCOPE_AGENT);
        for (;;) {
          bool ok = true;
#pragma unroll
          for (int i = 0; i < 8; ++i)
            ok &= ((uint32_t)hv[i] != 0u) && ((uint32_t)(hv[i] >> 32) != 0u);
          if (ok) break;
#pragma unroll
          for (int i = 0; i < 8; ++i)
            if (((uint32_t)hv[i] == 0u) || ((uint32_t)(hv[i] >> 32) == 0u))
              hv[i] = __hip_atomic_load(gp[i], __ATOMIC_RELAXED, __HIP_MEMORY_SCOPE_AGENT);
        }
#pragma unroll
        for (int i = 0; i < 4; ++i) {
          int v = i * 2048 + tid * 8;
          int bb = v >> 9, col = v & 511;
          unsigned long long* lp = (unsigned long long*)(hbuf + bb * 520 + col);
          lp[0] = hv[2 * i];
          lp[1] = hv[2 * i + 1];
        }
        __syncthreads();
#pragma unroll
        for (int kc = 0; kc < 16; ++kc) {
          short8 afrag = *(const short8*)(hbuf + l15 * 520 + kc * 32 + quad * 8);
          z0 = __builtin_amdgcn_mfma_f32_16x16x32_bf16(afrag, as_short8(uh[(nt0 * 16 + kc) * 64 + lane]), z0, 0, 0, 0);
          z1 = __builtin_amdgcn_mfma_f32_16x16x32_bf16(afrag, as_short8(uh[(nt1 * 16 + kc) * 64 + lane]), z1, 0, 0, 0);
        }
      }
#pragma unroll
      for (int r = 0; r < 4; ++r) {
        int m = quad * 4 + r;
        zbuf[m * 128 + nt0 * 16 + l15] = z0[r];
        zbuf[m * 128 + nt1 * 16 + l15] = z1[r];
      }
      *(uint4*)(xbuf + tid * 8) = xcur;
      __syncthreads();
      const float* zb = zbuf + pb * 128;
      uint32_t xi = *(const uint32_t*)(xbuf + (0 * 16 + pb) * 32 + pj);
      uint32_t xf = *(const uint32_t*)(xbuf + (1 * 16 + pb) * 32 + pj);
      uint32_t xg = *(const uint32_t*)(xbuf + (2 * 16 + pb) * 32 + pj);
      uint32_t xo = *(const uint32_t*)(xbuf + (3 * 16 + pb) * 32 + pj);
      float i0 = sigf(zb[pj] + bflo(xi)),      i1 = sigf(zb[pj + 1] + bfhi(xi));
      float f0 = sigf(zb[32 + pj] + bflo(xf)), f1 = sigf(zb[32 + pj + 1] + bfhi(xf));
      float g0 = sigf(zb[64 + pj] + bflo(xg)), g1 = sigf(zb[64 + pj + 1] + bfhi(xg));
      float o0 = sigf(zb[96 + pj] + bflo(xo)), o1 = sigf(zb[96 + pj + 1] + bfhi(xo));
      c0 = f0 * c0 + i0 * g0;
      c1 = f1 * c1 + i1 * g1;
      float h0 = o0 * sigf(c0);
      float h1 = o1 * sigf(c1);
      size_t oidx = ((size_t)pb * 1024 + t) * 1024 + dir * 512 + u0 + pj;
      uint32_t ha = f2bfbits(h0); ha += (ha == 0u);
      uint32_t hb = f2bfbits(h1); hb += (hb == 0u);
      uint32_t hp = ha | (hb << 16);
      __hip_atomic_store((uint32_t*)(ynext + oidx), hp, __ATOMIC_RELAXED, __HIP_MEMORY_SCOPE_AGENT);
      if (outf) { outf[oidx] = h0; outf[oidx + 1] = h1; }
      __syncthreads();   // vmcnt(0) drain: h visible before next poll (load-bearing)
      xcur = xnxt;
    }
    return;
  }

  // ================= gemm role: xz(l+1) written in place =================
  if (!xznext) return;
  uint4* Asl = (uint4*)smem;          // 1024 x 16B
  uint4* Bsl = ((uint4*)smem) + 1024; // 1024 x 16B
  int gb = blockIdx.x - 32;           // 0..95
  int wm = wv & 1, wn = wv >> 1;
  // tiles: g = kq*64 + inner; kq -> t-chunk c in middle-out readiness order;
  // inner = gdir*32 + ngi*2 + bg. Tile = batches [bg*8,+8) x t [c*16,+16).
  for (int g = gb; g < 4096; g += 96) {
    int kq = g >> 6, inner = g & 63;
    int c = (kq & 1) ? (31 - (kq >> 1)) : (32 + (kq >> 1));
    int tt0 = c * 16;
    int bg = inner & 1, ngi = (inner >> 1) & 15, gdir = inner >> 5;
    int n0 = ngi * 128;
    const __hip_bfloat16* Wd = Wtn + (size_t)gdir * 2048 * 1024;
    // PACERS (dir-correct): witness chain0 at step tt0+47 (stores t=step) and
    // chain1 at step 1055-tt0 (stores t=1023-step). swg0 of a chain at step S
    // implies every block of that chain completed S-1; each rec step ends
    // with a vmcnt(0) drain -> this tile's y rows are >=31 steps settled, and
    // the in-place xz writes below land >=32 steps behind the consumption of
    // the same addresses by the gdir chain.
    {
      int s0 = tt0 + 47;          if (s0 > 1023) s0 = 1023;
      int s1 = (1023 - tt0) + 32; if (s1 > 1023) s1 = 1023;
      const uint32_t* pp0 = (const uint32_t*)(ynext + ((size_t)(bg * 8) * 1024 + s0) * 1024);
      const uint32_t* pp1 = (const uint32_t*)(ynext + ((size_t)(bg * 8) * 1024 + (1023 - s1)) * 1024 + 512);
      while (__hip_atomic_load(pp0, __ATOMIC_RELAXED, __HIP_MEMORY_SCOPE_AGENT) == 0u)
        __builtin_amdgcn_s_sleep(32);
      while (__hip_atomic_load(pp1, __ATOMIC_RELAXED, __HIP_MEMORY_SCOPE_AGENT) == 0u)
        __builtin_amdgcn_s_sleep(32);
    }
    f32x4 acc[4][4] = {};
    for (int kb = 0; kb < 1024; kb += 64) {
      __syncthreads();
#pragma unroll
      for (int i = 0; i < 4; ++i) {
        int slot = i * 256 + tid;
        int ln = slot & 63, kc = (slot >> 6) & 1, mt = slot >> 7;
        int row = mt * 16 + (ln & 15);
        int kcol = kc * 32 + (ln >> 4) * 8;
        int bb = bg * 8 + (row >> 4), tt = tt0 + (row & 15);
        const unsigned long long* ap =
            (const unsigned long long*)(ynext + ((size_t)bb * 1024 + tt) * 1024 + kb + kcol);
        unsigned long long a0 = __hip_atomic_load(ap, __ATOMIC_RELAXED, __HIP_MEMORY_SCOPE_AGENT);
        unsigned long long a1 = __hip_atomic_load(ap + 1, __ATOMIC_RELAXED, __HIP_MEMORY_SCOPE_AGENT);
        while (!(qok(a0) & qok(a1))) {   // safety net; pacer makes this ~never spin
          __builtin_amdgcn_s_sleep(8);
          if (!qok(a0)) a0 = __hip_atomic_load(ap, __ATOMIC_RELAXED, __HIP_MEMORY_SCOPE_AGENT);
          if (!qok(a1)) a1 = __hip_atomic_load(ap + 1, __ATOMIC_RELAXED, __HIP_MEMORY_SCOPE_AGENT);
        }
        unsigned long long* asl = (unsigned long long*)&Asl[slot];
        asl[0] = a0; asl[1] = a1;
        Bsl[slot] = *(const uint4*)(Wd + (size_t)(n0 + row) * 1024 + kb + kcol);
      }
      __syncthreads();
#pragma unroll
      for (int kc = 0; kc < 2; ++kc) {
        short8 af[4], bf[4];
#pragma unroll
        for (int i = 0; i < 4; ++i) {
          af[i] = as_short8(Asl[((wm * 4 + i) * 2 + kc) * 64 + lane]);
          bf[i] = as_short8(Bsl[((wn * 4 + i) * 2 + kc) * 64 + lane]);
        }
#pragma unroll
        for (int i = 0; i < 4; ++i)
#pragma unroll
          for (int j = 0; j < 4; ++j)
            acc[i][j] = __builtin_amdgcn_mfma_f32_16x16x32_bf16(af[i], bf[j], acc[i][j], 0, 0, 0);
      }
    }
    int cq = lane >> 4, cn = lane & 15;
#pragma unroll
    for (int i = 0; i < 4; ++i)
#pragma unroll
      for (int j = 0; j < 4; ++j) {
        int n_g = n0 + (wn * 4 + j) * 16 + cn;
        int q = n_g >> 9, uu = n_g & 511, sw = uu >> 5, jj = uu & 31;
        float bv = biasn[gdir * 2048 + n_g];
#pragma unroll
        for (int r = 0; r < 4; ++r) {
          int ml = (wm * 4 + i) * 16 + cq * 4 + r;
          int bb = bg * 8 + (ml >> 4), tt = tt0 + (ml & 15);
          size_t addr = (((size_t)(gdir * 16 + sw) * 1024 + tt) * 2048) + (q * 16 + bb) * 32 + jj;
          xznext[addr] = __float2bfloat16(acc[i][j][r] + bv);
        }
      }
  }
}

// ---------------------------------------------------------------------------
extern "C" void kernel_launch(void* const* d_in, const int* in_sizes, int n_in,
                              void* d_out, int out_size, void* d_ws, size_t ws_size,
                              hipStream_t stream) {
  const float* x  = (const float*)d_in[0];   // [16][1024][1024]
  const float* W  = (const float*)d_in[1];   // [5][2][1024][2048]
  const float* Uh = (const float*)d_in[2];   // [5][2][512][2048]
  const float* b  = (const float*)d_in[3];   // [5][2][2048]

  char* ws = (char*)d_ws;
  size_t off = 0;
  __hip_bfloat16* yA = (__hip_bfloat16*)(ws + off); off += (size_t)16 * 1024 * 1024 * 2;
  __hip_bfloat16* yB = (__hip_bfloat16*)(ws + off); off += (size_t)16 * 1024 * 1024 * 2;
  __hip_bfloat16* xz = (__hip_bfloat16*)(ws + off); off += (size_t)2 * 16 * 1024 * 2048 * 2;
  __hip_bfloat16* Wt = (__hip_bfloat16*)(ws + off); off += (size_t)2 * 2048 * 1024 * 2;
  __hip_bfloat16* Ut = (__hip_bfloat16*)(ws + off); off += (size_t)2 * 2048 * 512 * 2;

  f32_to_bf16_k<<<dim3(16384), dim3(256), 0, stream>>>(x, yA, 4194304);
  hipFuncSetAttribute(reinterpret_cast<const void*>(lstm_rec_k),
                      hipFuncAttributeMaxDynamicSharedMemorySize, 160000);

  // prologue: layer-0 weights + xz(0) (nothing to hide under yet)
  transpose_bf16_k<<<dim3(16, 32, 2), dim3(256), 0, stream>>>(W, Wt, 1024);
  transpose_bf16_k<<<dim3(8, 32, 2),  dim3(256), 0, stream>>>(Uh, Ut, 512);
  hipMemsetAsync(yB, 0, (size_t)16 * 1024 * 1024 * 2, stream);   // rec(0) target
  gemm_xz_k<<<dim3(128, 32), dim3(256), 0, stream>>>(yA, Wt, b, xz);

  for (int l = 0; l < 5; ++l) {
    __hip_bfloat16* ycur = (l & 1) ? yB : yA;
    __hip_bfloat16* ynxt = (l & 1) ? yA : yB;
    if (l < 4)  // Wt(l) is dead (gemm(l) already ran) -> load Wt(l+1) for the fused gemm
      transpose_bf16_k<<<dim3(16, 32, 2), dim3(256), 0, stream>>>(
          W + (size_t)(l + 1) * 2 * 1024 * 2048, Wt, 1024);
    int grid = (l < 4) ? 128 : 32;
    lstm_rec_k<<<dim3(grid), dim3(256), 160000, stream>>>(
        Ut, xz, ynxt, (l == 4) ? (float*)d_out : nullptr,
        (l < 4) ? Wt : nullptr,
        (l < 4) ? (b + (size_t)(l + 1) * 2 * 2048) : nullptr,
        (l < 4) ? xz : nullptr);   // in-place xz(l+1)
    if (l < 4) {
      // Ut(l) consumed by rec(l) (stream-ordered) -> load Ut(l+1)
      transpose_bf16_k<<<dim3(8, 32, 2), dim3(256), 0, stream>>>(
          Uh + (size_t)(l + 1) * 2 * 512 * 2048, Ut, 512);
      // zero rec(l+1)'s target (ycur: dead since fused gemm(l) finished with it)
      hipMemsetAsync(ycur, 0, (size_t)16 * 1024 * 1024 * 2, stream);
    }
  }
}

// Round 12
// 13851.149 us; speedup vs baseline: 1.1637x; 1.1637x over previous
//
#include <hip/hip_runtime.h>
#include <hip/hip_bf16.h>
#include <stdint.h>

// ---------------------------------------------------------------------------
// Bidirectional 5-layer LSTM (all-sigmoid), B=16, T=1024, D=1024, U=512.
// R14 = byte-exact R3/R11 champion (13.87 ms, twice-reproduced). Session
// close: the rec kernel is latency-floor-bound (~2 serialized LLC RTs/step
// x 1024 steps x 5 layers), NOT memory- or compute-bound (HBM 0.9%, MFMA
// 1.1%). The complete failure ledger that establishes the floor:
//   R4  direct-frag loads     ✗ 64 live u64 -> spill (2.8x)
//   R5  drain removal         ✗ polls race stores -> LLC thrash (WRITE 3x)
//   R6  dir-alternation       ✗ 2x h-traffic, 2x phases
//   R7  XCD-local exchange    ✗ sc0 polls hit stale L1 (7.7x)
//   R8  in-wave gates         ✗ scattered h stores -> 6x HBM writes
//   R9  early-poll overlap    ✗ same thrash law as R5 (3-strike)
//   R10 bank-conflict fix     ✗ conflicts fully hidden under latency (-7%)
//   R12/R13 fused gemm(l+1)   ✗ LLC contention inflates rec RTs 32%;
//                               hiding 600us of GEMM costs 3.2ms (5x leverage)
// Load-bearing elements (do not touch): serialize-then-poll (store ->
// __syncthreads vmcnt(0) drain -> THEN poll); coalesced 64B h lines (16
// contiguous lanes); 16 blocks/dir x 32 units; minimal live regs across the
// poll; LLC as the exchange medium via agent-scope atomics.
// ---------------------------------------------------------------------------

typedef __attribute__((ext_vector_type(8))) short short8;
typedef __attribute__((ext_vector_type(4))) float f32x4;

union U128 { uint4 u; short8 s; };
static __device__ __forceinline__ short8 as_short8(uint4 v) { U128 x; x.u = v; return x.s; }

static __device__ __forceinline__ float sigf(float x) { return 1.0f / (1.0f + __expf(-x)); }

static __device__ __forceinline__ uint32_t f2bfbits(float f) {
  union { float f; uint32_t u; } x; x.f = f;
  return (x.u + 0x7fffu + ((x.u >> 16) & 1u)) >> 16;   // RNE; h in (0,1), no NaN
}
static __device__ __forceinline__ float bflo(uint32_t v) {
  union { uint32_t u; float f; } x; x.u = v << 16; return x.f;
}
static __device__ __forceinline__ float bfhi(uint32_t v) {
  union { uint32_t u; float f; } x; x.u = v & 0xffff0000u; return x.f;
}

// ---------------- x (fp32) -> bf16 ----------------
__global__ __launch_bounds__(256) void f32_to_bf16_k(const float* __restrict__ in,
                                                     __hip_bfloat16* __restrict__ out,
                                                     int n4) {
  int i = blockIdx.x * 256 + threadIdx.x;
  if (i < n4) {
    float4 v = ((const float4*)in)[i];
    uint32_t lo = f2bfbits(v.x) | (f2bfbits(v.y) << 16);
    uint32_t hi = f2bfbits(v.z) | (f2bfbits(v.w) << 16);
    ((uint2*)out)[i] = make_uint2(lo, hi);
  }
}

// ---------------- [2][R][2048] fp32 -> [2][2048][R] bf16 transpose ----------------
__global__ __launch_bounds__(256) void transpose_bf16_k(const float* __restrict__ in,
                                                        __hip_bfloat16* __restrict__ outp,
                                                        int R) {
  __shared__ float tile[64][65];
  int d = blockIdx.z;
  int k0 = blockIdx.x * 64;
  int c0 = blockIdx.y * 64;
  const float* inb = in + (size_t)d * R * 2048;
  __hip_bfloat16* ob = outp + (size_t)d * 2048 * R;
  int col = threadIdx.x & 63, rr = threadIdx.x >> 6;
#pragma unroll
  for (int i = 0; i < 16; ++i) {
    int r = rr + i * 4;
    tile[r][col] = inb[(size_t)(k0 + r) * 2048 + c0 + col];
  }
  __syncthreads();
#pragma unroll
  for (int i = 0; i < 16; ++i) {
    int r = rr + i * 4;
    ob[(size_t)(c0 + r) * R + k0 + col] = __float2bfloat16(tile[col][r]);
  }
}

// ---------------- xz GEMM: y[16384,1024] @ Wt[2][2048,1024]^T + b ----------------
// Output layout: xz[dir][swg(16)][t(1024)][q(4)][b(16)][j(32)]  (4KB per (dir,swg,t))
__global__ __launch_bounds__(256) void gemm_xz_k(const __hip_bfloat16* __restrict__ y,
                                                 const __hip_bfloat16* __restrict__ Wt,
                                                 const float* __restrict__ bias,
                                                 __hip_bfloat16* __restrict__ xz) {
  __shared__ uint4 Asl[8 * 2 * 64];
  __shared__ uint4 Bsl[8 * 2 * 64];
  int m0 = blockIdx.x * 128;
  int dir = blockIdx.y >> 4;
  int n0 = (blockIdx.y & 15) * 128;
  int tid = threadIdx.x, lane = tid & 63, wv = tid >> 6;
  int wm = wv & 1, wn = wv >> 1;
  const __hip_bfloat16* Wd = Wt + (size_t)dir * 2048 * 1024;
  f32x4 acc[4][4] = {};
  for (int kb = 0; kb < 1024; kb += 64) {
    __syncthreads();
#pragma unroll
    for (int i = 0; i < 4; ++i) {
      int slot = i * 256 + tid;
      int ln = slot & 63, kc = (slot >> 6) & 1, mt = slot >> 7;
      int row = mt * 16 + (ln & 15);
      int kk = kc * 32 + (ln >> 4) * 8;
      Asl[slot] = *(const uint4*)(y + (size_t)(m0 + row) * 1024 + kb + kk);
      Bsl[slot] = *(const uint4*)(Wd + (size_t)(n0 + row) * 1024 + kb + kk);
    }
    __syncthreads();
#pragma unroll
    for (int kc = 0; kc < 2; ++kc) {
      short8 af[4], bf[4];
#pragma unroll
      for (int i = 0; i < 4; ++i) {
        af[i] = as_short8(Asl[((wm * 4 + i) * 2 + kc) * 64 + lane]);
        bf[i] = as_short8(Bsl[((wn * 4 + i) * 2 + kc) * 64 + lane]);
      }
#pragma unroll
      for (int i = 0; i < 4; ++i)
#pragma unroll
        for (int j = 0; j < 4; ++j)
          acc[i][j] = __builtin_amdgcn_mfma_f32_16x16x32_bf16(af[i], bf[j], acc[i][j], 0, 0, 0);
    }
  }
  // epilogue: C/D layout col=lane&15, row=(lane>>4)*4+r  [m89-verified]
  int cq = lane >> 4, cn = lane & 15;
#pragma unroll
  for (int i = 0; i < 4; ++i)
#pragma unroll
    for (int j = 0; j < 4; ++j) {
      int n_g = n0 + (wn * 4 + j) * 16 + cn;
      int q = n_g >> 9, u = n_g & 511, swg = u >> 5, jj = u & 31;
      float bv = bias[dir * 2048 + n_g];
#pragma unroll
      for (int r = 0; r < 4; ++r) {
        int m = m0 + (wm * 4 + i) * 16 + cq * 4 + r;
        int b = m >> 10, t = m & 1023;
        size_t addr = (((size_t)(dir * 16 + swg) * 1024 + t) * 2048) + (q * 16 + b) * 32 + jj;
        xz[addr] = __float2bfloat16(acc[i][j][r] + bv);
      }
    }
}

// ---------------- persistent bidirectional recurrence ----------------
// 32 blocks: dir = blockIdx&1, slice = blockIdx>>1 (16 slices/dir, 32 u-cols).
// LDS: uh 128KB | hbuf 16x(512+8) bf16 = 16640B | zbuf 16x128 f32 = 8KB |
//      xbuf 2048 bf16 = 4KB  -> 160000 B total.
// Sentinel exchange: ynext pre-zeroed; h words never zero (guarded); readers
// poll the t-indexed data words directly until all nonzero.
__global__ __launch_bounds__(256) void lstm_rec_k(const __hip_bfloat16* __restrict__ Ut,  // [2][2048][512]
                                                  const __hip_bfloat16* __restrict__ xz,  // [dir][swg][t][2048]
                                                  __hip_bfloat16* __restrict__ ynext,     // [16][1024][1024], pre-zeroed
                                                  float* __restrict__ outf) {             // last layer or null
  extern __shared__ char smem[];
  uint4* uh = (uint4*)smem;                          // 8192 x 16B
  __hip_bfloat16* hbuf = (__hip_bfloat16*)(smem + 131072);  // [16][520]
  float* zbuf = (float*)(smem + 147712);             // [16][128]
  __hip_bfloat16* xbuf = (__hip_bfloat16*)(smem + 155904);  // [2048]
  int dir = blockIdx.x & 1;
  int swg = blockIdx.x >> 1;
  int u0 = swg * 32;
  int tid = threadIdx.x, lane = tid & 63, wv = tid >> 6;
  int quad = lane >> 4, l15 = lane & 15;
  const __hip_bfloat16* Ud = Ut + (size_t)dir * 2048 * 512;

  // fill LDS with Uh slice, pre-fragmented
#pragma unroll 4
  for (int i = 0; i < 32; ++i) {
    int slot = i * 256 + tid;
    int ls = slot & 63, kc = (slot >> 6) & 15, nt = slot >> 10;
    int n_g = (nt >> 1) * 512 + u0 + (nt & 1) * 16 + (ls & 15);
    int k = kc * 32 + (ls >> 4) * 8;
    uh[slot] = *(const uint4*)(Ud + (size_t)n_g * 512 + k);
  }
  __syncthreads();

  int nt0 = wv * 2, nt1 = wv * 2 + 1;
  int pb = tid >> 4, pj = (tid & 15) * 2;
  float c0 = 0.f, c1 = 0.f;

  int t0 = dir ? 1023 : 0;
  const uint4* xp0 = (const uint4*)(xz + ((size_t)(dir * 16 + swg) * 1024 + t0) * 2048) + tid;
  uint4 xcur = *xp0;

  for (int s = 0; s < 1024; ++s) {
    int t = dir ? (1023 - s) : s;
    // prefetch next step's xz (independent of the exchange; overlaps the poll)
    uint4 xnxt;
    if (s < 1023) {
      int tn = dir ? (1022 - s) : (s + 1);
      xnxt = *((const uint4*)(xz + ((size_t)(dir * 16 + swg) * 1024 + tn) * 2048) + tid);
    }
    f32x4 z0 = {}, z1 = {};
    if (s > 0) {
      int tprev = dir ? (t + 1) : (t - 1);
      // sentinel poll == coalesced h load: 64B/thread, retry words still zero.
      unsigned long long hv[8];
      const unsigned long long* gp[8];
#pragma unroll
      for (int i = 0; i < 4; ++i) {
        int v = i * 2048 + tid * 8;
        int b = v >> 9, col = v & 511;
        const unsigned long long* g =
            (const unsigned long long*)(ynext + ((size_t)b * 1024 + tprev) * 1024 + dir * 512 + col);
        gp[2 * i] = g;
        gp[2 * i + 1] = g + 1;
      }
#pragma unroll
      for (int i = 0; i < 8; ++i)
        hv[i] = __hip_atomic_load(gp[i], __ATOMIC_RELAXED, __HIP_MEMORY_SCOPE_AGENT);
      for (;;) {
        bool ok = true;
#pragma unroll
        for (int i = 0; i < 8; ++i)
          ok &= ((uint32_t)hv[i] != 0u) && ((uint32_t)(hv[i] >> 32) != 0u);
        if (ok) break;
#pragma unroll
        for (int i = 0; i < 8; ++i)
          if (((uint32_t)hv[i] == 0u) || ((uint32_t)(hv[i] >> 32) == 0u))
            hv[i] = __hip_atomic_load(gp[i], __ATOMIC_RELAXED, __HIP_MEMORY_SCOPE_AGENT);
      }
#pragma unroll
      for (int i = 0; i < 4; ++i) {
        int v = i * 2048 + tid * 8;
        int b = v >> 9, col = v & 511;
        unsigned long long* lp = (unsigned long long*)(hbuf + b * 520 + col);
        lp[0] = hv[2 * i];
        lp[1] = hv[2 * i + 1];
      }
      __syncthreads();
      // A-frags from LDS (b128, 2-way bank alias = free) + MFMA
#pragma unroll
      for (int kc = 0; kc < 16; ++kc) {
        short8 afrag = *(const short8*)(hbuf + l15 * 520 + kc * 32 + quad * 8);
        z0 = __builtin_amdgcn_mfma_f32_16x16x32_bf16(afrag, as_short8(uh[(nt0 * 16 + kc) * 64 + lane]), z0, 0, 0, 0);
        z1 = __builtin_amdgcn_mfma_f32_16x16x32_bf16(afrag, as_short8(uh[(nt1 * 16 + kc) * 64 + lane]), z1, 0, 0, 0);
      }
    }
    // publish z to zbuf; stage xz chunk to xbuf
#pragma unroll
    for (int r = 0; r < 4; ++r) {
      int m = quad * 4 + r;
      zbuf[m * 128 + nt0 * 16 + l15] = z0[r];
      zbuf[m * 128 + nt1 * 16 + l15] = z1[r];
    }
    *(uint4*)(xbuf + tid * 8) = xcur;
    __syncthreads();
    // gates: i,f,g,o = sigmoid; c = f*c + i*g; h = o*sigmoid(c)
    const float* zb = zbuf + pb * 128;
    uint32_t xi = *(const uint32_t*)(xbuf + (0 * 16 + pb) * 32 + pj);
    uint32_t xf = *(const uint32_t*)(xbuf + (1 * 16 + pb) * 32 + pj);
    uint32_t xg = *(const uint32_t*)(xbuf + (2 * 16 + pb) * 32 + pj);
    uint32_t xo = *(const uint32_t*)(xbuf + (3 * 16 + pb) * 32 + pj);
    float i0 = sigf(zb[pj] + bflo(xi)),      i1 = sigf(zb[pj + 1] + bfhi(xi));
    float f0 = sigf(zb[32 + pj] + bflo(xf)), f1 = sigf(zb[32 + pj + 1] + bfhi(xf));
    float g0 = sigf(zb[64 + pj] + bflo(xg)), g1 = sigf(zb[64 + pj + 1] + bfhi(xg));
    float o0 = sigf(zb[96 + pj] + bflo(xo)), o1 = sigf(zb[96 + pj + 1] + bfhi(xo));
    c0 = f0 * c0 + i0 * g0;
    c1 = f1 * c1 + i1 * g1;
    float h0 = o0 * sigf(c0);
    float h1 = o1 * sigf(c1);
    size_t oidx = ((size_t)pb * 1024 + t) * 1024 + dir * 512 + u0 + pj;
    // pack with zero-guard: bump exact-zero bf16 halves to the min subnormal
    // (error <= 9e-41) so a packed word can never be 0 -> sentinel-safe.
    uint32_t ha = f2bfbits(h0); ha += (ha == 0u);
    uint32_t hb = f2bfbits(h1); hb += (hb == 0u);
    uint32_t hp = ha | (hb << 16);
    __hip_atomic_store((uint32_t*)(ynext + oidx), hp, __ATOMIC_RELAXED, __HIP_MEMORY_SCOPE_AGENT);
    if (outf) { outf[oidx] = h0; outf[oidx + 1] = h1; }
    __syncthreads();   // drains vmcnt: h stores globally visible before next poll
    xcur = xnxt;
  }
}

// ---------------------------------------------------------------------------
extern "C" void kernel_launch(void* const* d_in, const int* in_sizes, int n_in,
                              void* d_out, int out_size, void* d_ws, size_t ws_size,
                              hipStream_t stream) {
  const float* x  = (const float*)d_in[0];   // [16][1024][1024]
  const float* W  = (const float*)d_in[1];   // [5][2][1024][2048]
  const float* Uh = (const float*)d_in[2];   // [5][2][512][2048]
  const float* b  = (const float*)d_in[3];   // [5][2][2048]

  char* ws = (char*)d_ws;
  size_t off = 0;
  __hip_bfloat16* yA = (__hip_bfloat16*)(ws + off); off += (size_t)16 * 1024 * 1024 * 2;
  __hip_bfloat16* yB = (__hip_bfloat16*)(ws + off); off += (size_t)16 * 1024 * 1024 * 2;
  __hip_bfloat16* xz = (__hip_bfloat16*)(ws + off); off += (size_t)2 * 16 * 1024 * 2048 * 2;
  __hip_bfloat16* Wt = (__hip_bfloat16*)(ws + off); off += (size_t)2 * 2048 * 1024 * 2;
  __hip_bfloat16* Ut = (__hip_bfloat16*)(ws + off); off += (size_t)2 * 2048 * 512 * 2;

  f32_to_bf16_k<<<dim3(16384), dim3(256), 0, stream>>>(x, yA, 4194304);
  hipFuncSetAttribute(reinterpret_cast<const void*>(lstm_rec_k),
                      hipFuncAttributeMaxDynamicSharedMemorySize, 160000);
  for (int l = 0; l < 5; ++l) {
    transpose_bf16_k<<<dim3(16, 32, 2), dim3(256), 0, stream>>>(W + (size_t)l * 2 * 1024 * 2048, Wt, 1024);
    transpose_bf16_k<<<dim3(8, 32, 2),  dim3(256), 0, stream>>>(Uh + (size_t)l * 2 * 512 * 2048, Ut, 512);
    __hip_bfloat16* ycur = (l & 1) ? yB : yA;
    __hip_bfloat16* ynxt = (l & 1) ? yA : yB;
    // zero ynxt: sentinel protocol requires unwritten h words to read as 0.
    hipMemsetAsync(ynxt, 0, (size_t)16 * 1024 * 1024 * 2, stream);
    gemm_xz_k<<<dim3(128, 32), dim3(256), 0, stream>>>(ycur, Wt, b + (size_t)l * 2 * 2048, xz);
    lstm_rec_k<<<dim3(32), dim3(256), 160000, stream>>>(
        Ut, xz, ynxt, (l == 4) ? (float*)d_out : nullptr);
  }
}